// Round 5
// baseline (194.602 us; speedup 1.0000x reference)
//
#include <hip/hip_runtime.h>

// Shapes (fixed): B=2, S=2048, D=1024, H=16, hd=64. M = B*S = 4096.
// ws layout (bf16 elems): qb[4M] | xb[4M] | wt[4M] | qkv[4096*3072] | vt[2][16][64][2048] | ctx[4M]

typedef __bf16 bf16_t;
typedef __attribute__((ext_vector_type(8))) __bf16 bf16x8;
typedef __attribute__((ext_vector_type(4))) __bf16 bf16x4;
typedef __attribute__((ext_vector_type(4))) float f32x4;

#define SCALE_LOG2E 0.045084220027780106f  // log2(e)/32
#define FIXED_MAX 8.0f

__device__ __forceinline__ void async_load16(const void* g, void* l) {
  __builtin_amdgcn_global_load_lds(
      (const __attribute__((address_space(1))) void*)g,
      (__attribute__((address_space(3))) void*)l, 16, 0, 0);
}

// ---- fused prep: blocks 0..4095 cast x/q_in; blocks 4096..5119 cast+transpose weights ----
__global__ void prep(const float* __restrict__ x, const float* __restrict__ q,
                     const float* __restrict__ w0, const float* __restrict__ w1,
                     const float* __restrict__ w2, const float* __restrict__ w3,
                     bf16_t* __restrict__ xb, bf16_t* __restrict__ qb,
                     bf16_t* __restrict__ wt) {
  const int bid = blockIdx.x;
  if (bid < 4096) {
    const float* src = (bid >= 2048) ? q : x;
    bf16_t* dst = (bid >= 2048) ? qb : xb;
    const size_t i = ((size_t)(bid & 2047) * 256 + threadIdx.x) * 8;
    float4 v0 = *(const float4*)(src + i);
    float4 v1 = *(const float4*)(src + i + 4);
    bf16x8 o;
    o[0] = (bf16_t)v0.x; o[1] = (bf16_t)v0.y; o[2] = (bf16_t)v0.z; o[3] = (bf16_t)v0.w;
    o[4] = (bf16_t)v1.x; o[5] = (bf16_t)v1.y; o[6] = (bf16_t)v1.z; o[7] = (bf16_t)v1.w;
    *(bf16x8*)(dst + i) = o;
  } else {
    const int wb = bid - 4096;
    const int z = wb >> 8;
    const float* W = z == 0 ? w0 : z == 1 ? w1 : z == 2 ? w2 : w3;
    bf16_t* dst = wt + (size_t)z * 1048576;
    const int r0 = ((wb >> 4) & 15) * 64, c0 = (wb & 15) * 64;
    __shared__ bf16_t t[64][72];
#pragma unroll
    for (int i = 0; i < 16; ++i) {
      int flat = i * 256 + threadIdx.x;
      int r = flat >> 6, c = flat & 63;
      t[c][r] = (bf16_t)W[(size_t)(r0 + r) * 1024 + c0 + c];
    }
    __syncthreads();
    const int c = threadIdx.x >> 2, seg = (threadIdx.x & 3) * 16;
    bf16x8 a = *(const bf16x8*)&t[c][seg];
    bf16x8 b = *(const bf16x8*)&t[c][seg + 8];
    bf16_t* drow = dst + (size_t)(c0 + c) * 1024 + r0 + seg;
    *(bf16x8*)drow = a;
    *(bf16x8*)(drow + 8) = b;
  }
}

// ---- GEMM, BK=64 single-buffer (2 barriers per 64-k: half the drains of BK=32) ----
// XOR-swizzled LDS (row stride 128B would be 16-way conflicted; swizzle makes reads 2-way=free).
// MODE 0: fused QKV 128x128 (3 blk/CU). MODE 2: out GEMM 128x64, fp32 (4 blk/CU).
template <int MODE>
__global__ __launch_bounds__(256, MODE == 2 ? 4 : 3) void gemm128(
    const bf16_t* __restrict__ Aq, const bf16_t* __restrict__ Ax,
    const bf16_t* __restrict__ Bt,
    bf16_t* __restrict__ Cq, bf16_t* __restrict__ Cvt, float* __restrict__ Cf) {
  constexpr int K = 1024;
  constexpr int NT = (MODE == 2) ? 2 : 4;
  constexpr int NROWS = NT * 32;
  const int n0 = blockIdx.x * NROWS;
  const int m0 = blockIdx.y * 128;
  const bf16_t* A = (MODE == 0 && n0 >= 1024) ? Ax : Aq;

  __shared__ bf16_t lA[128 * 64];    // 16 KB, swizzled
  __shared__ bf16_t lB[NROWS * 64];  // 16/8 KB, swizzled

  const int tid = threadIdx.x;
  const int w = tid >> 6, l = tid & 63;
  const int wm = (w & 1) * 64, wn = (w >> 1) * (NT * 16);
  const int fr = l & 15, fq = l >> 4;
  const int xr = fr & 7;
  const int srow = l >> 3;                 // 0..7 row within 8-row chunk
  const int swz = ((l & 7) ^ srow) * 8;    // XOR-swizzled source column

  const int gk0 = (fq ^ xr) * 8;           // ks=0 physical col group
  const int gk1 = ((4 + fq) ^ xr) * 8;     // ks=1

  f32x4 acc[4][NT] = {};

  for (int kt = 0; kt < K; kt += 64) {
    __syncthreads();
#pragma unroll
    for (int c = 0; c < 4; ++c) {
      const int ch = w * 4 + c;  // 16 chunks x 8 rows = 128 rows
      async_load16(A + (size_t)(m0 + ch * 8 + srow) * K + kt + swz, &lA[ch * 512]);
      if (NT == 4) {
        async_load16(Bt + (size_t)(n0 + ch * 8 + srow) * K + kt + swz, &lB[ch * 512]);
      } else if (c < 2) {
        const int bch = w * 2 + c;  // 8 chunks x 8 rows = 64 rows
        async_load16(Bt + (size_t)(n0 + bch * 8 + srow) * K + kt + swz, &lB[bch * 512]);
      }
    }
    __syncthreads();
    bf16x8 af[4][2], bfr[NT][2];
#pragma unroll
    for (int i = 0; i < 4; ++i) {
      const int row = (wm + i * 16 + fr) * 64;
      af[i][0] = *(const bf16x8*)&lA[row + gk0];
      af[i][1] = *(const bf16x8*)&lA[row + gk1];
    }
#pragma unroll
    for (int j = 0; j < NT; ++j) {
      const int row = (wn + j * 16 + fr) * 64;
      bfr[j][0] = *(const bf16x8*)&lB[row + gk0];
      bfr[j][1] = *(const bf16x8*)&lB[row + gk1];
    }
#pragma unroll
    for (int i = 0; i < 4; ++i)
#pragma unroll
      for (int j = 0; j < NT; ++j) {
        acc[i][j] = __builtin_amdgcn_mfma_f32_16x16x32_bf16(af[i][0], bfr[j][0], acc[i][j], 0, 0, 0);
        acc[i][j] = __builtin_amdgcn_mfma_f32_16x16x32_bf16(af[i][1], bfr[j][1], acc[i][j], 0, 0, 0);
      }
  }

  if (MODE == 2) {
#pragma unroll
    for (int i = 0; i < 4; ++i) {
      const int m = m0 + wm + i * 16 + fq * 4;
#pragma unroll
      for (int j = 0; j < NT; ++j) {
        const int n = n0 + wn + j * 16 + fr;
#pragma unroll
        for (int r = 0; r < 4; ++r) Cf[(size_t)(m + r) * 1024 + n] = acc[i][j][r];
      }
    }
  } else if (n0 < 2048) {
#pragma unroll
    for (int i = 0; i < 4; ++i) {
      const int m = m0 + wm + i * 16 + fq * 4;
#pragma unroll
      for (int j = 0; j < NT; ++j) {
        const int n = n0 + wn + j * 16 + fr;
#pragma unroll
        for (int r = 0; r < 4; ++r) Cq[(size_t)(m + r) * 3072 + n] = (bf16_t)acc[i][j][r];
      }
    }
  } else {
#pragma unroll
    for (int i = 0; i < 4; ++i) {
      const int mb = m0 + wm + i * 16 + fq * 4;
      const int bb = mb >> 11, ss = mb & 2047;
#pragma unroll
      for (int j = 0; j < NT; ++j) {
        const int nn = n0 - 2048 + wn + j * 16 + fr;
        const int hh = nn >> 6, dd = nn & 63;
        bf16x4 pk;
#pragma unroll
        for (int r = 0; r < 4; ++r) pk[r] = (bf16_t)acc[i][j][r];
        *(bf16x4*)(Cvt + (size_t)((bb * 16 + hh) * 64 + dd) * 2048 + ss) = pk;
      }
    }
  }
}

// ---- flash attention v12: v11 + CU-load-balanced block mapping ----
// R4 post-mortem: per-block work nkt=2qt+2 spans 2..32; with exactly 2 blocks/CU
// co-resident, the old "big first" mapping paired qt (15-a, 7-a) on one CU ->
// per-CU work 20..48 kt-units (1.41x critical path). New mapping: eff = bid<256 ?
// bid : 767-bid; qt=eff>>5, bh=eff&31. Pairs (i, i+256) share a CU (same i%8 XCD,
// same fill slot) and qt sums to 15 -> every CU gets 34 kt-units.
__global__ __launch_bounds__(512) void attn8w(const bf16_t* __restrict__ qkv,
                                              const bf16_t* __restrict__ vt,
                                              bf16_t* __restrict__ ctx) {
  const int bid = blockIdx.x;
  const int eff = (bid < 256) ? bid : (767 - bid);
  const int qt = eff >> 5;             // q-tile of 128 rows
  const int bh = eff & 31;
  const int b = bh >> 4, h = bh & 15;
  const int tid = threadIdx.x, w = tid >> 6, l = tid & 63;
  const int fr = l & 15, fq = l >> 4;
  const int qq4 = w & 3;               // q quarter (32 q)
  const int kh = w >> 2;               // key half (32 keys)

  __shared__ __align__(16) bf16_t lK[2][64 * 64];   // 16 KB
  __shared__ __align__(16) bf16_t lV[2][64 * 64];   // 16 KB
  __shared__ __align__(16) bf16_t lP[8][32 * 40];   // 20 KB
  __shared__ __align__(16) float lRed[4][16][68];   // 17.4 KB (reused per qs)

  const bf16_t* kg = qkv + (size_t)b * 2048 * 3072 + 1024 + h * 64;
  const bf16_t* vg = vt + (size_t)(b * 16 + h) * 64 * 2048;

  const int srow = l >> 3;
  const int swz = ((l & 7) ^ srow) * 8;
  const int xr = fr & 7;

  const int kbase = (kh * 32 + fr) * 64;
  const int g0 = (fq ^ xr) * 8, g1 = ((4 + fq) ^ xr) * 8;  // K col groups ks=0/1
  const int vbase = fr * 64;
  const int vg0 = ((kh * 4 + fq) ^ xr) * 8;                // V col group
  bf16_t* lPw = &lP[w][0];

  const int qw = qt * 128 + qq4 * 32;  // wave's first q row
  const int nkt = 2 * qt + 2;          // 64-key tiles covering q <= qt*128+127

  bf16x8 ones;
#pragma unroll
  for (int i = 0; i < 8; ++i) ones[i] = (bf16_t)1.0f;

  // Q fragments: 2 q-subtiles x 2 ks (all indices compile-time)
  bf16x8 qf[2][2];
#pragma unroll
  for (int qs = 0; qs < 2; ++qs)
#pragma unroll
    for (int ks = 0; ks < 2; ++ks)
      qf[qs][ks] = *(const bf16x8*)(qkv + (size_t)(b * 2048 + qw + qs * 16 + fr) * 3072 +
                                    h * 64 + ks * 32 + fq * 8);

  f32x4 o[2][4] = {};
  f32x4 li[2] = {};

  // running prefetch pointers (wave stages 8 rows of K and V per kt)
  const bf16_t* kp = kg + (size_t)(w * 8 + srow) * 3072 + swz;
  const bf16_t* vp = vg + (size_t)(w * 8 + srow) * 2048 + swz;

  async_load16(kp, &lK[0][w * 512]);
  async_load16(vp, &lV[0][w * 512]);
  kp += 64 * 3072;
  vp += 64;

  auto compute = [&](int kt, int buf) {
    const int kb = kt * 64 + kh * 32;
    if (kb > qw + 31) return;  // wave fully masked (above diagonal)
    const bf16_t* lKb = &lK[buf][0];
    const bf16_t* lVb = &lV[buf][0];
    f32x4 s[2][2] = {};
    __builtin_amdgcn_s_setprio(1);
#pragma unroll
    for (int t = 0; t < 2; ++t) {
      bf16x8 k0 = *(const bf16x8*)&lKb[kbase + t * 1024 + g0];
      bf16x8 k1 = *(const bf16x8*)&lKb[kbase + t * 1024 + g1];
#pragma unroll
      for (int qs = 0; qs < 2; ++qs) {
        s[qs][t] = __builtin_amdgcn_mfma_f32_16x16x32_bf16(k0, qf[qs][0], s[qs][t], 0, 0, 0);
        s[qs][t] = __builtin_amdgcn_mfma_f32_16x16x32_bf16(k1, qf[qs][1], s[qs][t], 0, 0, 0);
      }
    }
    __builtin_amdgcn_s_setprio(0);
#pragma unroll
    for (int qs = 0; qs < 2; ++qs) {
      const int qq = qw + qs * 16 + fr;
      const bool needmask = (kb + 31) > (qw + qs * 16);
#pragma unroll
      for (int t = 0; t < 2; ++t) {
        bf16x4 pk;
#pragma unroll
        for (int r = 0; r < 4; ++r) {
          float v = fmaf(s[qs][t][r], SCALE_LOG2E, -FIXED_MAX);
          if (needmask && (kb + t * 16 + fq * 4 + r > qq)) v = -1e30f;
          pk[r] = (bf16_t)__builtin_amdgcn_exp2f(v);
        }
        *(bf16x4*)&lPw[(qs * 16 + fr) * 40 + fq * 4 + t * 16] = pk;
      }
    }
    bf16x8 pf[2];
#pragma unroll
    for (int qs = 0; qs < 2; ++qs)
      pf[qs] = *(const bf16x8*)&lPw[(qs * 16 + fr) * 40 + fq * 8];
    __builtin_amdgcn_s_setprio(1);
#pragma unroll
    for (int dt = 0; dt < 4; ++dt) {
      bf16x8 vf = *(const bf16x8*)&lVb[vbase + dt * 1024 + vg0];
#pragma unroll
      for (int qs = 0; qs < 2; ++qs)
        o[qs][dt] = __builtin_amdgcn_mfma_f32_16x16x32_bf16(vf, pf[qs], o[qs][dt], 0, 0, 0);
    }
#pragma unroll
    for (int qs = 0; qs < 2; ++qs)
      li[qs] = __builtin_amdgcn_mfma_f32_16x16x32_bf16(ones, pf[qs], li[qs], 0, 0, 0);
    __builtin_amdgcn_s_setprio(0);
  };

  int kt = 0;
#pragma unroll 1
  while (true) {
    __syncthreads();
    if (kt + 1 < nkt) {
      async_load16(kp, &lK[1][w * 512]);
      async_load16(vp, &lV[1][w * 512]);
      kp += 64 * 3072; vp += 64;
    }
    compute(kt, 0);
    if (++kt >= nkt) break;
    __syncthreads();
    if (kt + 1 < nkt) {
      async_load16(kp, &lK[0][w * 512]);
      async_load16(vp, &lV[0][w * 512]);
      kp += 64 * 3072; vp += 64;
    }
    compute(kt, 1);
    if (++kt >= nkt) break;
  }

  // key-half reduction per q-subtile: kh=1 writes partials, kh=0 adds + stores.
  // STATIC qs (rule #20): hand-unrolled; barriers in uniform control flow are legal.
#pragma unroll
  for (int qs = 0; qs < 2; ++qs) {
    __syncthreads();
    if (kh) {
#pragma unroll
      for (int dt = 0; dt < 4; ++dt)
        *(f32x4*)&lRed[qq4][fr][dt * 16 + fq * 4] = o[qs][dt];
      if (fq == 0) lRed[qq4][fr][64] = li[qs][0];
    }
    __syncthreads();
    if (!kh) {
      const float lsum = li[qs][0] + lRed[qq4][fr][64];
      const float inv = 1.f / lsum;
      bf16_t* cb = ctx + (size_t)(b * 2048 + qw + qs * 16 + fr) * 1024 + h * 64;
#pragma unroll
      for (int dt = 0; dt < 4; ++dt) {
        f32x4 v = o[qs][dt] + *(f32x4*)&lRed[qq4][fr][dt * 16 + fq * 4];
        bf16x4 ov;
#pragma unroll
        for (int r = 0; r < 4; ++r) ov[r] = (bf16_t)(v[r] * inv);
        *(bf16x4*)(cb + dt * 16 + fq * 4) = ov;
      }
    }
  }
}

extern "C" void kernel_launch(void* const* d_in, const int* in_sizes, int n_in,
                              void* d_out, int out_size, void* d_ws, size_t ws_size,
                              hipStream_t stream) {
  const float* x  = (const float*)d_in[0];
  const float* q  = (const float*)d_in[1];
  const float* WQ = (const float*)d_in[2];
  const float* WK = (const float*)d_in[3];
  const float* WV = (const float*)d_in[4];
  const float* WO = (const float*)d_in[5];
  float* out = (float*)d_out;

  bf16_t* qb  = (bf16_t*)d_ws;
  bf16_t* xb  = qb + 4194304;
  bf16_t* wt  = xb + 4194304;
  bf16_t* qkv = wt + 4194304;
  bf16_t* vtp = qkv + (size_t)4096 * 3072;
  bf16_t* ctx = vtp + 4194304;

  prep<<<dim3(5120), 256, 0, stream>>>(x, q, WQ, WK, WV, WO, xb, qb, wt);
  gemm128<0><<<dim3(24, 32), 256, 0, stream>>>(qb, xb, wt, qkv, vtp, nullptr);
  attn8w<<<dim3(512), 512, 0, stream>>>(qkv, vtp, ctx);
  gemm128<2><<<dim3(16, 32), 256, 0, stream>>>(ctx, ctx, wt + (size_t)3072 * 1024,
                                               nullptr, nullptr, out);
}

// Round 6
// 188.933 us; speedup vs baseline: 1.0300x; 1.0300x over previous
//
#include <hip/hip_runtime.h>

// Shapes (fixed): B=2, S=2048, D=1024, H=16, hd=64. M = B*S = 4096.
// ws layout (bf16 elems): qb[4M] | xb[4M] | wt[4M] | qkv[4096*3072] | vt[2][16][64][2048] | ctx[4M]

typedef __bf16 bf16_t;
typedef __attribute__((ext_vector_type(8))) __bf16 bf16x8;
typedef __attribute__((ext_vector_type(4))) __bf16 bf16x4;
typedef __attribute__((ext_vector_type(4))) float f32x4;

#define SCALE_LOG2E 0.045084220027780106f  // log2(e)/32
#define FIXED_MAX 8.0f

__device__ __forceinline__ void async_load16(const void* g, void* l) {
  __builtin_amdgcn_global_load_lds(
      (const __attribute__((address_space(1))) void*)g,
      (__attribute__((address_space(3))) void*)l, 16, 0, 0);
}

// ---- fused prep: blocks 0..4095 cast x/q_in; blocks 4096..5119 cast+transpose weights ----
__global__ void prep(const float* __restrict__ x, const float* __restrict__ q,
                     const float* __restrict__ w0, const float* __restrict__ w1,
                     const float* __restrict__ w2, const float* __restrict__ w3,
                     bf16_t* __restrict__ xb, bf16_t* __restrict__ qb,
                     bf16_t* __restrict__ wt) {
  const int bid = blockIdx.x;
  if (bid < 4096) {
    const float* src = (bid >= 2048) ? q : x;
    bf16_t* dst = (bid >= 2048) ? qb : xb;
    const size_t i = ((size_t)(bid & 2047) * 256 + threadIdx.x) * 8;
    float4 v0 = *(const float4*)(src + i);
    float4 v1 = *(const float4*)(src + i + 4);
    bf16x8 o;
    o[0] = (bf16_t)v0.x; o[1] = (bf16_t)v0.y; o[2] = (bf16_t)v0.z; o[3] = (bf16_t)v0.w;
    o[4] = (bf16_t)v1.x; o[5] = (bf16_t)v1.y; o[6] = (bf16_t)v1.z; o[7] = (bf16_t)v1.w;
    *(bf16x8*)(dst + i) = o;
  } else {
    const int wb = bid - 4096;
    const int z = wb >> 8;
    const float* W = z == 0 ? w0 : z == 1 ? w1 : z == 2 ? w2 : w3;
    bf16_t* dst = wt + (size_t)z * 1048576;
    const int r0 = ((wb >> 4) & 15) * 64, c0 = (wb & 15) * 64;
    __shared__ bf16_t t[64][72];
#pragma unroll
    for (int i = 0; i < 16; ++i) {
      int flat = i * 256 + threadIdx.x;
      int r = flat >> 6, c = flat & 63;
      t[c][r] = (bf16_t)W[(size_t)(r0 + r) * 1024 + c0 + c];
    }
    __syncthreads();
    const int c = threadIdx.x >> 2, seg = (threadIdx.x & 3) * 16;
    bf16x8 a = *(const bf16x8*)&t[c][seg];
    bf16x8 b = *(const bf16x8*)&t[c][seg + 8];
    bf16_t* drow = dst + (size_t)(c0 + c) * 1024 + r0 + seg;
    *(bf16x8*)drow = a;
    *(bf16x8*)(drow + 8) = b;
  }
}

// ---- GEMM, BK=64 single-buffer (2 barriers per 64-k: half the drains of BK=32) ----
// XOR-swizzled LDS (row stride 128B would be 16-way conflicted; swizzle makes reads 2-way=free).
// MODE 0: fused QKV 128x128 (3 blk/CU). MODE 2: out GEMM 128x64, fp32 (4 blk/CU).
template <int MODE>
__global__ __launch_bounds__(256, MODE == 2 ? 4 : 3) void gemm128(
    const bf16_t* __restrict__ Aq, const bf16_t* __restrict__ Ax,
    const bf16_t* __restrict__ Bt,
    bf16_t* __restrict__ Cq, bf16_t* __restrict__ Cvt, float* __restrict__ Cf) {
  constexpr int K = 1024;
  constexpr int NT = (MODE == 2) ? 2 : 4;
  constexpr int NROWS = NT * 32;
  const int n0 = blockIdx.x * NROWS;
  const int m0 = blockIdx.y * 128;
  const bf16_t* A = (MODE == 0 && n0 >= 1024) ? Ax : Aq;

  __shared__ bf16_t lA[128 * 64];    // 16 KB, swizzled
  __shared__ bf16_t lB[NROWS * 64];  // 16/8 KB, swizzled

  const int tid = threadIdx.x;
  const int w = tid >> 6, l = tid & 63;
  const int wm = (w & 1) * 64, wn = (w >> 1) * (NT * 16);
  const int fr = l & 15, fq = l >> 4;
  const int xr = fr & 7;
  const int srow = l >> 3;                 // 0..7 row within 8-row chunk
  const int swz = ((l & 7) ^ srow) * 8;    // XOR-swizzled source column

  const int gk0 = (fq ^ xr) * 8;           // ks=0 physical col group
  const int gk1 = ((4 + fq) ^ xr) * 8;     // ks=1

  f32x4 acc[4][NT] = {};

  for (int kt = 0; kt < K; kt += 64) {
    __syncthreads();
#pragma unroll
    for (int c = 0; c < 4; ++c) {
      const int ch = w * 4 + c;  // 16 chunks x 8 rows = 128 rows
      async_load16(A + (size_t)(m0 + ch * 8 + srow) * K + kt + swz, &lA[ch * 512]);
      if (NT == 4) {
        async_load16(Bt + (size_t)(n0 + ch * 8 + srow) * K + kt + swz, &lB[ch * 512]);
      } else if (c < 2) {
        const int bch = w * 2 + c;  // 8 chunks x 8 rows = 64 rows
        async_load16(Bt + (size_t)(n0 + bch * 8 + srow) * K + kt + swz, &lB[bch * 512]);
      }
    }
    __syncthreads();
    bf16x8 af[4][2], bfr[NT][2];
#pragma unroll
    for (int i = 0; i < 4; ++i) {
      const int row = (wm + i * 16 + fr) * 64;
      af[i][0] = *(const bf16x8*)&lA[row + gk0];
      af[i][1] = *(const bf16x8*)&lA[row + gk1];
    }
#pragma unroll
    for (int j = 0; j < NT; ++j) {
      const int row = (wn + j * 16 + fr) * 64;
      bfr[j][0] = *(const bf16x8*)&lB[row + gk0];
      bfr[j][1] = *(const bf16x8*)&lB[row + gk1];
    }
#pragma unroll
    for (int i = 0; i < 4; ++i)
#pragma unroll
      for (int j = 0; j < NT; ++j) {
        acc[i][j] = __builtin_amdgcn_mfma_f32_16x16x32_bf16(af[i][0], bfr[j][0], acc[i][j], 0, 0, 0);
        acc[i][j] = __builtin_amdgcn_mfma_f32_16x16x32_bf16(af[i][1], bfr[j][1], acc[i][j], 0, 0, 0);
      }
  }

  if (MODE == 2) {
#pragma unroll
    for (int i = 0; i < 4; ++i) {
      const int m = m0 + wm + i * 16 + fq * 4;
#pragma unroll
      for (int j = 0; j < NT; ++j) {
        const int n = n0 + wn + j * 16 + fr;
#pragma unroll
        for (int r = 0; r < 4; ++r) Cf[(size_t)(m + r) * 1024 + n] = acc[i][j][r];
      }
    }
  } else if (n0 < 2048) {
#pragma unroll
    for (int i = 0; i < 4; ++i) {
      const int m = m0 + wm + i * 16 + fq * 4;
#pragma unroll
      for (int j = 0; j < NT; ++j) {
        const int n = n0 + wn + j * 16 + fr;
#pragma unroll
        for (int r = 0; r < 4; ++r) Cq[(size_t)(m + r) * 3072 + n] = (bf16_t)acc[i][j][r];
      }
    }
  } else {
#pragma unroll
    for (int i = 0; i < 4; ++i) {
      const int mb = m0 + wm + i * 16 + fq * 4;
      const int bb = mb >> 11, ss = mb & 2047;
#pragma unroll
      for (int j = 0; j < NT; ++j) {
        const int nn = n0 - 2048 + wn + j * 16 + fr;
        const int hh = nn >> 6, dd = nn & 63;
        bf16x4 pk;
#pragma unroll
        for (int r = 0; r < 4; ++r) pk[r] = (bf16_t)acc[i][j][r];
        *(bf16x4*)(Cvt + (size_t)((bb * 16 + hh) * 64 + dd) * 2048 + ss) = pk;
      }
    }
  }
}

// ---- flash attention v13: v12 + counted-vmcnt barriers (T4) ----
// R5 post-mortem: no pipe saturated (Mfma 15%, VALU 30%, LDS ~36%, HBM 7%) ->
// latency/barrier-bound. __syncthreads = s_waitcnt vmcnt(0)+s_barrier drained the
// just-issued K/V DMA at EVERY barrier. New per-kt pattern:
//   s_barrier                    (WAR: prev readers of the buffer we overwrite are done)
//   issue next-tile DMA          (stays in flight across the whole compute)
//   s_waitcnt vmcnt(2)           (waits only PREVIOUS tile's 2 loads - issued ~800cy ago)
//   s_barrier                    (publish all waves' load completion)
//   compute(kt)
// Last iteration re-issues the final tile into the dead buffer (advance clamped; never
// read; drained by the epilogue __syncthreads). Per-wave in-loop VMEM is exactly the
// 2 global_load_lds per iter, so vmcnt(2) is exact (no scratch: VGPR=60, WRITE=8MB).
__global__ __launch_bounds__(512) void attn8w(const bf16_t* __restrict__ qkv,
                                              const bf16_t* __restrict__ vt,
                                              bf16_t* __restrict__ ctx) {
  const int bid = blockIdx.x;
  const int eff = (bid < 256) ? bid : (767 - bid);
  const int qt = eff >> 5;             // q-tile of 128 rows
  const int bh = eff & 31;
  const int b = bh >> 4, h = bh & 15;
  const int tid = threadIdx.x, w = tid >> 6, l = tid & 63;
  const int fr = l & 15, fq = l >> 4;
  const int qq4 = w & 3;               // q quarter (32 q)
  const int kh = w >> 2;               // key half (32 keys)

  __shared__ __align__(16) bf16_t lK[2][64 * 64];   // 16 KB
  __shared__ __align__(16) bf16_t lV[2][64 * 64];   // 16 KB
  __shared__ __align__(16) bf16_t lP[8][32 * 40];   // 20 KB
  __shared__ __align__(16) float lRed[4][16][68];   // 17.4 KB (reused per qs)

  const bf16_t* kg = qkv + (size_t)b * 2048 * 3072 + 1024 + h * 64;
  const bf16_t* vg = vt + (size_t)(b * 16 + h) * 64 * 2048;

  const int srow = l >> 3;
  const int swz = ((l & 7) ^ srow) * 8;
  const int xr = fr & 7;

  const int kbase = (kh * 32 + fr) * 64;
  const int g0 = (fq ^ xr) * 8, g1 = ((4 + fq) ^ xr) * 8;  // K col groups ks=0/1
  const int vbase = fr * 64;
  const int vg0 = ((kh * 4 + fq) ^ xr) * 8;                // V col group
  bf16_t* lPw = &lP[w][0];

  const int qw = qt * 128 + qq4 * 32;  // wave's first q row
  const int nkt = 2 * qt + 2;          // 64-key tiles covering q <= qt*128+127

  bf16x8 ones;
#pragma unroll
  for (int i = 0; i < 8; ++i) ones[i] = (bf16_t)1.0f;

  // Q fragments: 2 q-subtiles x 2 ks (all indices compile-time)
  bf16x8 qf[2][2];
#pragma unroll
  for (int qs = 0; qs < 2; ++qs)
#pragma unroll
    for (int ks = 0; ks < 2; ++ks)
      qf[qs][ks] = *(const bf16x8*)(qkv + (size_t)(b * 2048 + qw + qs * 16 + fr) * 3072 +
                                    h * 64 + ks * 32 + fq * 8);

  f32x4 o[2][4] = {};
  f32x4 li[2] = {};

  // running prefetch pointers (wave stages 8 rows of K and V per kt)
  const bf16_t* kp = kg + (size_t)(w * 8 + srow) * 3072 + swz;
  const bf16_t* vp = vg + (size_t)(w * 8 + srow) * 2048 + swz;

  async_load16(kp, &lK[0][w * 512]);
  async_load16(vp, &lV[0][w * 512]);
  kp += 64 * 3072;
  vp += 64;

  auto compute = [&](int kt, int buf) {
    const int kb = kt * 64 + kh * 32;
    if (kb > qw + 31) return;  // wave fully masked (above diagonal)
    const bf16_t* lKb = &lK[buf][0];
    const bf16_t* lVb = &lV[buf][0];
    f32x4 s[2][2] = {};
    __builtin_amdgcn_s_setprio(1);
#pragma unroll
    for (int t = 0; t < 2; ++t) {
      bf16x8 k0 = *(const bf16x8*)&lKb[kbase + t * 1024 + g0];
      bf16x8 k1 = *(const bf16x8*)&lKb[kbase + t * 1024 + g1];
#pragma unroll
      for (int qs = 0; qs < 2; ++qs) {
        s[qs][t] = __builtin_amdgcn_mfma_f32_16x16x32_bf16(k0, qf[qs][0], s[qs][t], 0, 0, 0);
        s[qs][t] = __builtin_amdgcn_mfma_f32_16x16x32_bf16(k1, qf[qs][1], s[qs][t], 0, 0, 0);
      }
    }
    __builtin_amdgcn_s_setprio(0);
#pragma unroll
    for (int qs = 0; qs < 2; ++qs) {
      const int qq = qw + qs * 16 + fr;
      const bool needmask = (kb + 31) > (qw + qs * 16);
#pragma unroll
      for (int t = 0; t < 2; ++t) {
        bf16x4 pk;
#pragma unroll
        for (int r = 0; r < 4; ++r) {
          float v = fmaf(s[qs][t][r], SCALE_LOG2E, -FIXED_MAX);
          if (needmask && (kb + t * 16 + fq * 4 + r > qq)) v = -1e30f;
          pk[r] = (bf16_t)__builtin_amdgcn_exp2f(v);
        }
        *(bf16x4*)&lPw[(qs * 16 + fr) * 40 + fq * 4 + t * 16] = pk;
      }
    }
    bf16x8 pf[2];
#pragma unroll
    for (int qs = 0; qs < 2; ++qs)
      pf[qs] = *(const bf16x8*)&lPw[(qs * 16 + fr) * 40 + fq * 8];
    __builtin_amdgcn_s_setprio(1);
#pragma unroll
    for (int dt = 0; dt < 4; ++dt) {
      bf16x8 vf = *(const bf16x8*)&lVb[vbase + dt * 1024 + vg0];
#pragma unroll
      for (int qs = 0; qs < 2; ++qs)
        o[qs][dt] = __builtin_amdgcn_mfma_f32_16x16x32_bf16(vf, pf[qs], o[qs][dt], 0, 0, 0);
    }
#pragma unroll
    for (int qs = 0; qs < 2; ++qs)
      li[qs] = __builtin_amdgcn_mfma_f32_16x16x32_bf16(ones, pf[qs], li[qs], 0, 0, 0);
    __builtin_amdgcn_s_setprio(0);
  };

  int kt = 0;
#pragma unroll 1
  while (true) {
    __builtin_amdgcn_s_barrier();
    async_load16(kp, &lK[1][w * 512]);
    async_load16(vp, &lV[1][w * 512]);
    if (kt + 2 < nkt) { kp += 64 * 3072; vp += 64; }
    asm volatile("s_waitcnt vmcnt(2)" ::: "memory");
    __builtin_amdgcn_s_barrier();
    __builtin_amdgcn_sched_barrier(0);
    compute(kt, 0);
    if (++kt >= nkt) break;
    __builtin_amdgcn_s_barrier();
    async_load16(kp, &lK[0][w * 512]);
    async_load16(vp, &lV[0][w * 512]);
    if (kt + 2 < nkt) { kp += 64 * 3072; vp += 64; }
    asm volatile("s_waitcnt vmcnt(2)" ::: "memory");
    __builtin_amdgcn_s_barrier();
    __builtin_amdgcn_sched_barrier(0);
    compute(kt, 1);
    if (++kt >= nkt) break;
  }

  // key-half reduction per q-subtile: kh=1 writes partials, kh=0 adds + stores.
  // STATIC qs (rule #20); __syncthreads here also drains the final junk prefetch.
#pragma unroll
  for (int qs = 0; qs < 2; ++qs) {
    __syncthreads();
    if (kh) {
#pragma unroll
      for (int dt = 0; dt < 4; ++dt)
        *(f32x4*)&lRed[qq4][fr][dt * 16 + fq * 4] = o[qs][dt];
      if (fq == 0) lRed[qq4][fr][64] = li[qs][0];
    }
    __syncthreads();
    if (!kh) {
      const float lsum = li[qs][0] + lRed[qq4][fr][64];
      const float inv = 1.f / lsum;
      bf16_t* cb = ctx + (size_t)(b * 2048 + qw + qs * 16 + fr) * 1024 + h * 64;
#pragma unroll
      for (int dt = 0; dt < 4; ++dt) {
        f32x4 v = o[qs][dt] + *(f32x4*)&lRed[qq4][fr][dt * 16 + fq * 4];
        bf16x4 ov;
#pragma unroll
        for (int r = 0; r < 4; ++r) ov[r] = (bf16_t)(v[r] * inv);
        *(bf16x4*)(cb + dt * 16 + fq * 4) = ov;
      }
    }
  }
}

extern "C" void kernel_launch(void* const* d_in, const int* in_sizes, int n_in,
                              void* d_out, int out_size, void* d_ws, size_t ws_size,
                              hipStream_t stream) {
  const float* x  = (const float*)d_in[0];
  const float* q  = (const float*)d_in[1];
  const float* WQ = (const float*)d_in[2];
  const float* WK = (const float*)d_in[3];
  const float* WV = (const float*)d_in[4];
  const float* WO = (const float*)d_in[5];
  float* out = (float*)d_out;

  bf16_t* qb  = (bf16_t*)d_ws;
  bf16_t* xb  = qb + 4194304;
  bf16_t* wt  = xb + 4194304;
  bf16_t* qkv = wt + 4194304;
  bf16_t* vtp = qkv + (size_t)4096 * 3072;
  bf16_t* ctx = vtp + 4194304;

  prep<<<dim3(5120), 256, 0, stream>>>(x, q, WQ, WK, WV, WO, xb, qb, wt);
  gemm128<0><<<dim3(24, 32), 256, 0, stream>>>(qb, xb, wt, qkv, vtp, nullptr);
  attn8w<<<dim3(512), 512, 0, stream>>>(qkv, vtp, ctx);
  gemm128<2><<<dim3(16, 32), 256, 0, stream>>>(ctx, ctx, wt + (size_t)3072 * 1024,
                                               nullptr, nullptr, out);
}

// Round 7
// 186.807 us; speedup vs baseline: 1.0417x; 1.0114x over previous
//
#include <hip/hip_runtime.h>

// Shapes (fixed): B=2, S=2048, D=1024, H=16, hd=64. M = B*S = 4096.
// ws layout (bf16 elems): qb[4M] | xb[4M] | wt[4M] | qkv[4096*3072] | vt[2][16][64][2048] | ctx[4M]

typedef __bf16 bf16_t;
typedef __attribute__((ext_vector_type(8))) __bf16 bf16x8;
typedef __attribute__((ext_vector_type(4))) __bf16 bf16x4;
typedef __attribute__((ext_vector_type(4))) float f32x4;

#define SCALE_LOG2E 0.045084220027780106f  // log2(e)/32
#define FIXED_MAX 8.0f

__device__ __forceinline__ void async_load16(const void* g, void* l) {
  __builtin_amdgcn_global_load_lds(
      (const __attribute__((address_space(1))) void*)g,
      (__attribute__((address_space(3))) void*)l, 16, 0, 0);
}

// ---- fused prep: blocks 0..4095 cast x/q_in; blocks 4096..5119 cast+transpose weights ----
__global__ void prep(const float* __restrict__ x, const float* __restrict__ q,
                     const float* __restrict__ w0, const float* __restrict__ w1,
                     const float* __restrict__ w2, const float* __restrict__ w3,
                     bf16_t* __restrict__ xb, bf16_t* __restrict__ qb,
                     bf16_t* __restrict__ wt) {
  const int bid = blockIdx.x;
  if (bid < 4096) {
    const float* src = (bid >= 2048) ? q : x;
    bf16_t* dst = (bid >= 2048) ? qb : xb;
    const size_t i = ((size_t)(bid & 2047) * 256 + threadIdx.x) * 8;
    float4 v0 = *(const float4*)(src + i);
    float4 v1 = *(const float4*)(src + i + 4);
    bf16x8 o;
    o[0] = (bf16_t)v0.x; o[1] = (bf16_t)v0.y; o[2] = (bf16_t)v0.z; o[3] = (bf16_t)v0.w;
    o[4] = (bf16_t)v1.x; o[5] = (bf16_t)v1.y; o[6] = (bf16_t)v1.z; o[7] = (bf16_t)v1.w;
    *(bf16x8*)(dst + i) = o;
  } else {
    const int wb = bid - 4096;
    const int z = wb >> 8;
    const float* W = z == 0 ? w0 : z == 1 ? w1 : z == 2 ? w2 : w3;
    bf16_t* dst = wt + (size_t)z * 1048576;
    const int r0 = ((wb >> 4) & 15) * 64, c0 = (wb & 15) * 64;
    __shared__ bf16_t t[64][72];
#pragma unroll
    for (int i = 0; i < 16; ++i) {
      int flat = i * 256 + threadIdx.x;
      int r = flat >> 6, c = flat & 63;
      t[c][r] = (bf16_t)W[(size_t)(r0 + r) * 1024 + c0 + c];
    }
    __syncthreads();
    const int c = threadIdx.x >> 2, seg = (threadIdx.x & 3) * 16;
    bf16x8 a = *(const bf16x8*)&t[c][seg];
    bf16x8 b = *(const bf16x8*)&t[c][seg + 8];
    bf16_t* drow = dst + (size_t)(c0 + c) * 1024 + r0 + seg;
    *(bf16x8*)drow = a;
    *(bf16x8*)(drow + 8) = b;
  }
}

// ---- QKV GEMM v2: 256x256 8-phase schedule (T2+T3+T4+T5), BK=64, 8 waves ----
// Derived from the m201 template invariants:
//  - per 8-phase iteration: compute tiles {tt (buf0, ph0-3), tt+1 (buf1, ph4-7)}
//  - stage unit u (A-quadrant u rows {32u..+32, 128+32u..+32} + B rows {64u..+64},
//    2 gload_lds/thread) only in the phase AFTER quadrant u's last read:
//    ph0: unit3 of tt+1 | ph1-4: units0-3 of tt+2 | ph5-7: units0-2 of tt+3
//  - vmcnt(6) at end of ph3 / ph7 only (= 3 stage-units in flight); never 0 in loop
//  - tail: stage targets >=16 clamp source to tile-2 (junk lands in just-read regions)
// Grid 12x16 (BN=256 divides 1024 so a block's A matrix (qb vs xb) is uniform).
__global__ __launch_bounds__(512) void gemm256(
    const bf16_t* __restrict__ Aq, const bf16_t* __restrict__ Ax,
    const bf16_t* __restrict__ Bt,
    bf16_t* __restrict__ Cq, bf16_t* __restrict__ Cvt) {
  const int n0 = blockIdx.x * 256, m0 = blockIdx.y * 256;
  const bf16_t* A = (blockIdx.x < 4) ? Aq : Ax;

  __shared__ bf16_t lA[2][256 * 64];  // 64 KB
  __shared__ bf16_t lB[2][256 * 64];  // 64 KB

  const int tid = threadIdx.x, w = tid >> 6, l = tid & 63;
  const int wrow = w & 1, wcol = w >> 1;
  const int fr = l & 15, fq = l >> 4, xr = fr & 7;
  const int srow = l >> 3;
  const int swz = ((l & 7) ^ srow) * 8;
  const int gk0 = (fq ^ xr) * 8, gk1 = ((4 + fq) ^ xr) * 8;

  const int chA = (w < 4) ? w : (16 + (w - 4));  // + 4*u
  const int chB = w;                             // + 8*u

  f32x4 acc[8][4] = {};

  auto stageA = [&](int t, int u, int buf) {
    const int ch = chA + 4 * u;
    async_load16(A + (size_t)(m0 + ch * 8 + srow) * 1024 + t * 64 + swz,
                 &lA[buf][ch * 512]);
  };
  auto stageB = [&](int t, int u, int buf) {
    const int ch = chB + 8 * u;
    async_load16(Bt + (size_t)(n0 + ch * 8 + srow) * 1024 + t * 64 + swz,
                 &lB[buf][ch * 512]);
  };

  // prologue: tile0 full (8 loads) + tile1 units 0-2 (6 loads); wait tile0
#pragma unroll
  for (int u = 0; u < 4; ++u) { stageA(0, u, 0); stageB(0, u, 0); }
#pragma unroll
  for (int u = 0; u < 3; ++u) { stageA(1, u, 1); stageB(1, u, 1); }
  asm volatile("s_waitcnt vmcnt(6)" ::: "memory");
  __builtin_amdgcn_s_barrier();

  bf16x8 bf[4][2];

#pragma unroll 1
  for (int tt = 0; tt < 16; tt += 2) {
#pragma unroll
    for (int ph = 0; ph < 8; ++ph) {
      const int q = ph & 3;
      const int buf = ph >> 2;
      // ds reads: B once per K-tile (ph0/ph4), A quadrant q each phase
      if (q == 0) {
#pragma unroll
        for (int j = 0; j < 4; ++j) {
          const int row = (wcol * 64 + j * 16 + fr) * 64;
          bf[j][0] = *(const bf16x8*)&lB[buf][row + gk0];
          bf[j][1] = *(const bf16x8*)&lB[buf][row + gk1];
        }
      }
      bf16x8 af[2][2];
#pragma unroll
      for (int ii = 0; ii < 2; ++ii) {
        const int row = (wrow * 128 + (q * 2 + ii) * 16 + fr) * 64;
        af[ii][0] = *(const bf16x8*)&lA[buf][row + gk0];
        af[ii][1] = *(const bf16x8*)&lA[buf][row + gk1];
      }
      // stage one unit (2 loads)
      {
        int st, su, sbuf;
        if (ph == 0)      { st = tt + 1; su = 3;      sbuf = 1; }
        else if (ph <= 4) { st = tt + 2; su = ph - 1; sbuf = 0; }
        else              { st = tt + 3; su = ph - 5; sbuf = 1; }
        const int sts = (st < 16) ? st : (st - 2);  // tail clamp (junk, safe region)
        stageA(sts, su, sbuf);
        stageB(sts, su, sbuf);
      }
      __builtin_amdgcn_s_barrier();
      asm volatile("s_waitcnt lgkmcnt(0)" ::: "memory");
      __builtin_amdgcn_sched_barrier(0);
      __builtin_amdgcn_s_setprio(1);
#pragma unroll
      for (int ii = 0; ii < 2; ++ii)
#pragma unroll
        for (int j = 0; j < 4; ++j) {
          acc[q * 2 + ii][j] = __builtin_amdgcn_mfma_f32_16x16x32_bf16(
              af[ii][0], bf[j][0], acc[q * 2 + ii][j], 0, 0, 0);
          acc[q * 2 + ii][j] = __builtin_amdgcn_mfma_f32_16x16x32_bf16(
              af[ii][1], bf[j][1], acc[q * 2 + ii][j], 0, 0, 0);
        }
      __builtin_amdgcn_s_setprio(0);
      __builtin_amdgcn_sched_barrier(0);
      if (q == 3) asm volatile("s_waitcnt vmcnt(6)" ::: "memory");
      __builtin_amdgcn_s_barrier();
    }
  }
  asm volatile("s_waitcnt vmcnt(0)" ::: "memory");  // drain tail junk loads

  // epilogue
  if (n0 < 2048) {  // Q/K region -> qkv rows stride 3072
#pragma unroll
    for (int i = 0; i < 8; ++i) {
      const int m = m0 + wrow * 128 + i * 16 + fq * 4;
#pragma unroll
      for (int j = 0; j < 4; ++j) {
        const int n = n0 + wcol * 64 + j * 16 + fr;
#pragma unroll
        for (int r = 0; r < 4; ++r)
          Cq[(size_t)(m + r) * 3072 + n] = (bf16_t)acc[i][j][r];
      }
    }
  } else {          // V region -> vt scatter [b*16+h][d][s]
#pragma unroll
    for (int i = 0; i < 8; ++i) {
      const int mb = m0 + wrow * 128 + i * 16 + fq * 4;
      const int bb = mb >> 11, ss = mb & 2047;
#pragma unroll
      for (int j = 0; j < 4; ++j) {
        const int nn = n0 - 2048 + wcol * 64 + j * 16 + fr;
        const int hh = nn >> 6, dd = nn & 63;
        bf16x4 pk;
#pragma unroll
        for (int r = 0; r < 4; ++r) pk[r] = (bf16_t)acc[i][j][r];
        *(bf16x4*)(Cvt + (size_t)((bb * 16 + hh) * 64 + dd) * 2048 + ss) = pk;
      }
    }
  }
}

// ---- out GEMM, 128x64 BK=64 single-buffer (kept; 256^2 would be 25% CU util) ----
template <int MODE>
__global__ __launch_bounds__(256, 4) void gemm128(
    const bf16_t* __restrict__ Aq, const bf16_t* __restrict__ Ax,
    const bf16_t* __restrict__ Bt,
    bf16_t* __restrict__ Cq, bf16_t* __restrict__ Cvt, float* __restrict__ Cf) {
  constexpr int K = 1024;
  constexpr int NT = 2;
  constexpr int NROWS = NT * 32;
  const int n0 = blockIdx.x * NROWS;
  const int m0 = blockIdx.y * 128;
  const bf16_t* A = Aq;

  __shared__ bf16_t lA[128 * 64];
  __shared__ bf16_t lB[NROWS * 64];

  const int tid = threadIdx.x;
  const int w = tid >> 6, l = tid & 63;
  const int wm = (w & 1) * 64, wn = (w >> 1) * (NT * 16);
  const int fr = l & 15, fq = l >> 4;
  const int xr = fr & 7;
  const int srow = l >> 3;
  const int swz = ((l & 7) ^ srow) * 8;

  const int gk0 = (fq ^ xr) * 8;
  const int gk1 = ((4 + fq) ^ xr) * 8;

  f32x4 acc[4][NT] = {};

  for (int kt = 0; kt < K; kt += 64) {
    __syncthreads();
#pragma unroll
    for (int c = 0; c < 4; ++c) {
      const int ch = w * 4 + c;
      async_load16(A + (size_t)(m0 + ch * 8 + srow) * K + kt + swz, &lA[ch * 512]);
      if (c < 2) {
        const int bch = w * 2 + c;
        async_load16(Bt + (size_t)(n0 + bch * 8 + srow) * K + kt + swz, &lB[bch * 512]);
      }
    }
    __syncthreads();
    bf16x8 af[4][2], bfr[NT][2];
#pragma unroll
    for (int i = 0; i < 4; ++i) {
      const int row = (wm + i * 16 + fr) * 64;
      af[i][0] = *(const bf16x8*)&lA[row + gk0];
      af[i][1] = *(const bf16x8*)&lA[row + gk1];
    }
#pragma unroll
    for (int j = 0; j < NT; ++j) {
      const int row = (wn + j * 16 + fr) * 64;
      bfr[j][0] = *(const bf16x8*)&lB[row + gk0];
      bfr[j][1] = *(const bf16x8*)&lB[row + gk1];
    }
#pragma unroll
    for (int i = 0; i < 4; ++i)
#pragma unroll
      for (int j = 0; j < NT; ++j) {
        acc[i][j] = __builtin_amdgcn_mfma_f32_16x16x32_bf16(af[i][0], bfr[j][0], acc[i][j], 0, 0, 0);
        acc[i][j] = __builtin_amdgcn_mfma_f32_16x16x32_bf16(af[i][1], bfr[j][1], acc[i][j], 0, 0, 0);
      }
  }

#pragma unroll
  for (int i = 0; i < 4; ++i) {
    const int m = m0 + wm + i * 16 + fq * 4;
#pragma unroll
    for (int j = 0; j < NT; ++j) {
      const int n = n0 + wn + j * 16 + fr;
#pragma unroll
      for (int r = 0; r < 4; ++r) Cf[(size_t)(m + r) * 1024 + n] = acc[i][j][r];
    }
  }
}

// ---- flash attention v7 (REVERTED to R0 proven-best: 181.0 us total) ----
__global__ __launch_bounds__(512, 4) void attn8w(const bf16_t* __restrict__ qkv,
                                                 const bf16_t* __restrict__ vt,
                                                 bf16_t* __restrict__ ctx) {
  const int p = blockIdx.y;
  const int bh = blockIdx.x;
  const int b = bh >> 4, h = bh & 15;
  const int tid = threadIdx.x, w = tid >> 6, l = tid & 63;
  const int fr = l & 15, fq = l >> 4;
  const int qq4 = w & 3;          // q quarter (16 q)
  const int kh = w >> 2;          // key half (32 keys)

  __shared__ __align__(16) bf16_t lK[2][64 * 64];
  __shared__ __align__(16) bf16_t lV[2][64 * 64];
  __shared__ __align__(16) bf16_t lP[8][16 * 40];
  __shared__ __align__(16) float lRed[4][16][68];

  const bf16_t* kg = qkv + (size_t)b * 2048 * 3072 + 1024 + h * 64;
  const bf16_t* vg = vt + (size_t)(b * 16 + h) * 64 * 2048;

  const int srow = l >> 3;
  const int swz = ((l & 7) ^ srow) * 8;
  const int xr = fr & 7;

  const int kbase = (kh * 32 + fr) * 64;
  const int g0 = (fq ^ xr) * 8, g1 = ((4 + fq) ^ xr) * 8;     // K col groups ks=0/1
  const int vbase = fr * 64;
  const int vg0 = ((kh * 4 + fq) ^ xr) * 8;                   // V col group
  const int pwr = fr * 40 + fq * 4;                           // lP write base
  const int prd = fr * 40 + fq * 8;                           // lP read base
  bf16_t* lPw = &lP[w][0];

  bf16x8 ones;
#pragma unroll
  for (int i = 0; i < 8; ++i) ones[i] = (bf16_t)1.0f;

#pragma unroll 1
  for (int phase = 0; phase < 2; ++phase) {
    const int qt = (phase == 0) ? (16 + p) : (15 - p);
    const int qw = qt * 64 + qq4 * 16;

    bf16x8 qf[2];
#pragma unroll
    for (int ks = 0; ks < 2; ++ks)
      qf[ks] = *(const bf16x8*)(qkv + (size_t)(b * 2048 + qw + fr) * 3072 +
                                h * 64 + ks * 32 + fq * 8);

    f32x4 o[4] = {};
    f32x4 liacc = {};

    // running prefetch pointers (wave stages 8 rows of K and V)
    const bf16_t* kp = kg + (size_t)(w * 8 + srow) * 3072 + swz;
    const bf16_t* vp = vg + (size_t)(w * 8 + srow) * 2048 + swz;

    if (phase == 1) __syncthreads();
    async_load16(kp, &lK[0][w * 512]);
    async_load16(vp, &lV[0][w * 512]);
    kp += 64 * 3072;
    vp += 64;

    auto compute = [&](int kt, int buf) {
      const int kb = kt * 64 + kh * 32;
      if (kb > qw + 15) return;  // wave fully masked (above diagonal)
      const bf16_t* lKb = &lK[buf][0];
      const bf16_t* lVb = &lV[buf][0];
      f32x4 s[2] = {};
#pragma unroll
      for (int t = 0; t < 2; ++t) {
        bf16x8 k0 = *(const bf16x8*)&lKb[kbase + t * 1024 + g0];
        bf16x8 k1 = *(const bf16x8*)&lKb[kbase + t * 1024 + g1];
        s[t] = __builtin_amdgcn_mfma_f32_16x16x32_bf16(k0, qf[0], s[t], 0, 0, 0);
        s[t] = __builtin_amdgcn_mfma_f32_16x16x32_bf16(k1, qf[1], s[t], 0, 0, 0);
      }
      const int qq = qw + fr;
      const bool needmask = (kb + 31) > qw;
#pragma unroll
      for (int t = 0; t < 2; ++t) {
        bf16x4 pk;
#pragma unroll
        for (int r = 0; r < 4; ++r) {
          float v = fmaf(s[t][r], SCALE_LOG2E, -FIXED_MAX);
          if (needmask && (kb + t * 16 + fq * 4 + r > qq)) v = -1e30f;
          pk[r] = (bf16_t)__builtin_amdgcn_exp2f(v);
        }
        *(bf16x4*)&lPw[pwr + t * 16] = pk;
      }
      bf16x8 pf = *(const bf16x8*)&lPw[prd];
#pragma unroll
      for (int dt = 0; dt < 4; ++dt) {
        bf16x8 vf = *(const bf16x8*)&lVb[vbase + dt * 1024 + vg0];
        o[dt] = __builtin_amdgcn_mfma_f32_16x16x32_bf16(vf, pf, o[dt], 0, 0, 0);
      }
      liacc = __builtin_amdgcn_mfma_f32_16x16x32_bf16(ones, pf, liacc, 0, 0, 0);
    };

    int kt = 0;
#pragma unroll 1
    while (true) {
      __syncthreads();
      if (kt < qt) {
        async_load16(kp, &lK[1][w * 512]);
        async_load16(vp, &lV[1][w * 512]);
        kp += 64 * 3072; vp += 64;
      }
      compute(kt, 0);
      if (++kt > qt) break;
      __syncthreads();
      if (kt < qt) {
        async_load16(kp, &lK[0][w * 512]);
        async_load16(vp, &lV[0][w * 512]);
        kp += 64 * 3072; vp += 64;
      }
      compute(kt, 1);
      if (++kt > qt) break;
    }

    // key-half reduction: kh=1 writes partials, kh=0 adds + stores
    __syncthreads();
    if (kh) {
#pragma unroll
      for (int dt = 0; dt < 4; ++dt)
        *(f32x4*)&lRed[qq4][fr][dt * 16 + fq * 4] = o[dt];
      if (fq == 0) lRed[qq4][fr][64] = liacc[0];
    }
    __syncthreads();
    if (!kh) {
      const float lsum = liacc[0] + lRed[qq4][fr][64];
      const float inv = 1.f / lsum;
      bf16_t* cb = ctx + (size_t)(b * 2048 + qw + fr) * 1024 + h * 64;
#pragma unroll
      for (int dt = 0; dt < 4; ++dt) {
        f32x4 v = o[dt] + *(f32x4*)&lRed[qq4][fr][dt * 16 + fq * 4];
        bf16x4 ov;
#pragma unroll
        for (int r = 0; r < 4; ++r) ov[r] = (bf16_t)(v[r] * inv);
        *(bf16x4*)(cb + dt * 16 + fq * 4) = ov;
      }
    }
  }
}

extern "C" void kernel_launch(void* const* d_in, const int* in_sizes, int n_in,
                              void* d_out, int out_size, void* d_ws, size_t ws_size,
                              hipStream_t stream) {
  const float* x  = (const float*)d_in[0];
  const float* q  = (const float*)d_in[1];
  const float* WQ = (const float*)d_in[2];
  const float* WK = (const float*)d_in[3];
  const float* WV = (const float*)d_in[4];
  const float* WO = (const float*)d_in[5];
  float* out = (float*)d_out;

  bf16_t* qb  = (bf16_t*)d_ws;
  bf16_t* xb  = qb + 4194304;
  bf16_t* wt  = xb + 4194304;
  bf16_t* qkv = wt + 4194304;
  bf16_t* vtp = qkv + (size_t)4096 * 3072;
  bf16_t* ctx = vtp + 4194304;

  prep<<<dim3(5120), 256, 0, stream>>>(x, q, WQ, WK, WV, WO, xb, qb, wt);
  gemm256<<<dim3(12, 16), 512, 0, stream>>>(qb, xb, wt, qkv, vtp);
  attn8w<<<dim3(32, 16), 512, 0, stream>>>(qkv, vtp, ctx);
  gemm128<2><<<dim3(16, 32), 256, 0, stream>>>(ctx, ctx, wt + (size_t)3072 * 1024,
                                               nullptr, nullptr, out);
}

// Round 8
// 185.041 us; speedup vs baseline: 1.0517x; 1.0095x over previous
//
#include <hip/hip_runtime.h>

// Shapes (fixed): B=2, S=2048, D=1024, H=16, hd=64. M = B*S = 4096.
// ws layout (bf16 elems): qb[4M] | xb[4M] | wt[4M] | qkv[4096*3072] | vt[2][16][64][2048] | ctx[4M]

typedef __bf16 bf16_t;
typedef __attribute__((ext_vector_type(8))) __bf16 bf16x8;
typedef __attribute__((ext_vector_type(4))) __bf16 bf16x4;
typedef __attribute__((ext_vector_type(4))) float f32x4;

#define SCALE_LOG2E 0.045084220027780106f  // log2(e)/32
#define FIXED_MAX 8.0f

__device__ __forceinline__ void async_load16(const void* g, void* l) {
  __builtin_amdgcn_global_load_lds(
      (const __attribute__((address_space(1))) void*)g,
      (__attribute__((address_space(3))) void*)l, 16, 0, 0);
}

// ---- fused prep: blocks 0..4095 cast x/q_in; blocks 4096..5119 cast+transpose weights ----
__global__ void prep(const float* __restrict__ x, const float* __restrict__ q,
                     const float* __restrict__ w0, const float* __restrict__ w1,
                     const float* __restrict__ w2, const float* __restrict__ w3,
                     bf16_t* __restrict__ xb, bf16_t* __restrict__ qb,
                     bf16_t* __restrict__ wt) {
  const int bid = blockIdx.x;
  if (bid < 4096) {
    const float* src = (bid >= 2048) ? q : x;
    bf16_t* dst = (bid >= 2048) ? qb : xb;
    const size_t i = ((size_t)(bid & 2047) * 256 + threadIdx.x) * 8;
    float4 v0 = *(const float4*)(src + i);
    float4 v1 = *(const float4*)(src + i + 4);
    bf16x8 o;
    o[0] = (bf16_t)v0.x; o[1] = (bf16_t)v0.y; o[2] = (bf16_t)v0.z; o[3] = (bf16_t)v0.w;
    o[4] = (bf16_t)v1.x; o[5] = (bf16_t)v1.y; o[6] = (bf16_t)v1.z; o[7] = (bf16_t)v1.w;
    *(bf16x8*)(dst + i) = o;
  } else {
    const int wb = bid - 4096;
    const int z = wb >> 8;
    const float* W = z == 0 ? w0 : z == 1 ? w1 : z == 2 ? w2 : w3;
    bf16_t* dst = wt + (size_t)z * 1048576;
    const int r0 = ((wb >> 4) & 15) * 64, c0 = (wb & 15) * 64;
    __shared__ bf16_t t[64][72];
#pragma unroll
    for (int i = 0; i < 16; ++i) {
      int flat = i * 256 + threadIdx.x;
      int r = flat >> 6, c = flat & 63;
      t[c][r] = (bf16_t)W[(size_t)(r0 + r) * 1024 + c0 + c];
    }
    __syncthreads();
    const int c = threadIdx.x >> 2, seg = (threadIdx.x & 3) * 16;
    bf16x8 a = *(const bf16x8*)&t[c][seg];
    bf16x8 b = *(const bf16x8*)&t[c][seg + 8];
    bf16_t* drow = dst + (size_t)(c0 + c) * 1024 + r0 + seg;
    *(bf16x8*)drow = a;
    *(bf16x8*)(drow + 8) = b;
  }
}

// ---- GEMM, BK=64 single-buffer (2 barriers per 64-k: half the drains of BK=32) ----
// XOR-swizzled LDS (row stride 128B would be 16-way conflicted; swizzle makes reads 2-way=free).
// MODE 0: fused QKV 128x128 (3 blk/CU). MODE 2: out GEMM 128x64, fp32 (4 blk/CU).
template <int MODE>
__global__ __launch_bounds__(256, MODE == 2 ? 4 : 3) void gemm128(
    const bf16_t* __restrict__ Aq, const bf16_t* __restrict__ Ax,
    const bf16_t* __restrict__ Bt,
    bf16_t* __restrict__ Cq, bf16_t* __restrict__ Cvt, float* __restrict__ Cf) {
  constexpr int K = 1024;
  constexpr int NT = (MODE == 2) ? 2 : 4;
  constexpr int NROWS = NT * 32;
  const int n0 = blockIdx.x * NROWS;
  const int m0 = blockIdx.y * 128;
  const bf16_t* A = (MODE == 0 && n0 >= 1024) ? Ax : Aq;

  __shared__ bf16_t lA[128 * 64];    // 16 KB, swizzled
  __shared__ bf16_t lB[NROWS * 64];  // 16/8 KB, swizzled

  const int tid = threadIdx.x;
  const int w = tid >> 6, l = tid & 63;
  const int wm = (w & 1) * 64, wn = (w >> 1) * (NT * 16);
  const int fr = l & 15, fq = l >> 4;
  const int xr = fr & 7;
  const int srow = l >> 3;                 // 0..7 row within 8-row chunk
  const int swz = ((l & 7) ^ srow) * 8;    // XOR-swizzled source column

  const int gk0 = (fq ^ xr) * 8;           // ks=0 physical col group
  const int gk1 = ((4 + fq) ^ xr) * 8;     // ks=1

  f32x4 acc[4][NT] = {};

  for (int kt = 0; kt < K; kt += 64) {
    __syncthreads();
#pragma unroll
    for (int c = 0; c < 4; ++c) {
      const int ch = w * 4 + c;  // 16 chunks x 8 rows = 128 rows
      async_load16(A + (size_t)(m0 + ch * 8 + srow) * K + kt + swz, &lA[ch * 512]);
      if (NT == 4) {
        async_load16(Bt + (size_t)(n0 + ch * 8 + srow) * K + kt + swz, &lB[ch * 512]);
      } else if (c < 2) {
        const int bch = w * 2 + c;  // 8 chunks x 8 rows = 64 rows
        async_load16(Bt + (size_t)(n0 + bch * 8 + srow) * K + kt + swz, &lB[bch * 512]);
      }
    }
    __syncthreads();
    bf16x8 af[4][2], bfr[NT][2];
#pragma unroll
    for (int i = 0; i < 4; ++i) {
      const int row = (wm + i * 16 + fr) * 64;
      af[i][0] = *(const bf16x8*)&lA[row + gk0];
      af[i][1] = *(const bf16x8*)&lA[row + gk1];
    }
#pragma unroll
    for (int j = 0; j < NT; ++j) {
      const int row = (wn + j * 16 + fr) * 64;
      bfr[j][0] = *(const bf16x8*)&lB[row + gk0];
      bfr[j][1] = *(const bf16x8*)&lB[row + gk1];
    }
#pragma unroll
    for (int i = 0; i < 4; ++i)
#pragma unroll
      for (int j = 0; j < NT; ++j) {
        acc[i][j] = __builtin_amdgcn_mfma_f32_16x16x32_bf16(af[i][0], bfr[j][0], acc[i][j], 0, 0, 0);
        acc[i][j] = __builtin_amdgcn_mfma_f32_16x16x32_bf16(af[i][1], bfr[j][1], acc[i][j], 0, 0, 0);
      }
  }

  if (MODE == 2) {
#pragma unroll
    for (int i = 0; i < 4; ++i) {
      const int m = m0 + wm + i * 16 + fq * 4;
#pragma unroll
      for (int j = 0; j < NT; ++j) {
        const int n = n0 + wn + j * 16 + fr;
#pragma unroll
        for (int r = 0; r < 4; ++r) Cf[(size_t)(m + r) * 1024 + n] = acc[i][j][r];
      }
    }
  } else if (n0 < 2048) {
#pragma unroll
    for (int i = 0; i < 4; ++i) {
      const int m = m0 + wm + i * 16 + fq * 4;
#pragma unroll
      for (int j = 0; j < NT; ++j) {
        const int n = n0 + wn + j * 16 + fr;
#pragma unroll
        for (int r = 0; r < 4; ++r) Cq[(size_t)(m + r) * 3072 + n] = (bf16_t)acc[i][j][r];
      }
    }
  } else {
#pragma unroll
    for (int i = 0; i < 4; ++i) {
      const int mb = m0 + wm + i * 16 + fq * 4;
      const int bb = mb >> 11, ss = mb & 2047;
#pragma unroll
      for (int j = 0; j < NT; ++j) {
        const int nn = n0 - 2048 + wn + j * 16 + fr;
        const int hh = nn >> 6, dd = nn & 63;
        bf16x4 pk;
#pragma unroll
        for (int r = 0; r < 4; ++r) pk[r] = (bf16_t)acc[i][j][r];
        *(bf16x4*)(Cvt + (size_t)((bb * 16 + hh) * 64 + dd) * 2048 + ss) = pk;
      }
    }
  }
}

// ---- flash attention v14: v7 structure + counted-vmcnt barriers (T4, proven +1.3us on v12) ----
// Only change vs v7: each kt's {__syncthreads; guarded prefetch} becomes
//   s_barrier                  (WAR: prior readers of the overwritten buffer passed here)
//   always-issue 2 DMA loads   (pointer advance clamped at last real tile; re-issues are
//                               value-identical or land in a dead buffer)
//   s_waitcnt vmcnt(2)         (waits only the PREVIOUS tile's pair, issued ~1 iter ago)
//   s_barrier + sched_barrier  (publish; pin compute after)
// Junk loads are drained by the reduction __syncthreads (phase 0) / phase-1 entry
// __syncthreads. Per-wave in-loop VMEM = exactly 2 loads/iter -> vmcnt(2) exact.
__global__ __launch_bounds__(512, 4) void attn8w(const bf16_t* __restrict__ qkv,
                                                 const bf16_t* __restrict__ vt,
                                                 bf16_t* __restrict__ ctx) {
  const int p = blockIdx.y;
  const int bh = blockIdx.x;
  const int b = bh >> 4, h = bh & 15;
  const int tid = threadIdx.x, w = tid >> 6, l = tid & 63;
  const int fr = l & 15, fq = l >> 4;
  const int qq4 = w & 3;          // q quarter (16 q)
  const int kh = w >> 2;          // key half (32 keys)

  __shared__ __align__(16) bf16_t lK[2][64 * 64];
  __shared__ __align__(16) bf16_t lV[2][64 * 64];
  __shared__ __align__(16) bf16_t lP[8][16 * 40];
  __shared__ __align__(16) float lRed[4][16][68];

  const bf16_t* kg = qkv + (size_t)b * 2048 * 3072 + 1024 + h * 64;
  const bf16_t* vg = vt + (size_t)(b * 16 + h) * 64 * 2048;

  const int srow = l >> 3;
  const int swz = ((l & 7) ^ srow) * 8;
  const int xr = fr & 7;

  const int kbase = (kh * 32 + fr) * 64;
  const int g0 = (fq ^ xr) * 8, g1 = ((4 + fq) ^ xr) * 8;     // K col groups ks=0/1
  const int vbase = fr * 64;
  const int vg0 = ((kh * 4 + fq) ^ xr) * 8;                   // V col group
  const int pwr = fr * 40 + fq * 4;                           // lP write base
  const int prd = fr * 40 + fq * 8;                           // lP read base
  bf16_t* lPw = &lP[w][0];

  bf16x8 ones;
#pragma unroll
  for (int i = 0; i < 8; ++i) ones[i] = (bf16_t)1.0f;

#pragma unroll 1
  for (int phase = 0; phase < 2; ++phase) {
    const int qt = (phase == 0) ? (16 + p) : (15 - p);
    const int qw = qt * 64 + qq4 * 16;

    bf16x8 qf[2];
#pragma unroll
    for (int ks = 0; ks < 2; ++ks)
      qf[ks] = *(const bf16x8*)(qkv + (size_t)(b * 2048 + qw + fr) * 3072 +
                                h * 64 + ks * 32 + fq * 8);

    f32x4 o[4] = {};
    f32x4 liacc = {};

    // running prefetch pointers (wave stages 8 rows of K and V)
    const bf16_t* kp = kg + (size_t)(w * 8 + srow) * 3072 + swz;
    const bf16_t* vp = vg + (size_t)(w * 8 + srow) * 2048 + swz;

    if (phase == 1) __syncthreads();   // drains phase-0 junk prefetch (vmcnt(0))
    async_load16(kp, &lK[0][w * 512]);
    async_load16(vp, &lV[0][w * 512]);
    kp += 64 * 3072;
    vp += 64;

    auto compute = [&](int kt, int buf) {
      const int kb = kt * 64 + kh * 32;
      if (kb > qw + 15) return;  // wave fully masked (above diagonal)
      const bf16_t* lKb = &lK[buf][0];
      const bf16_t* lVb = &lV[buf][0];
      f32x4 s[2] = {};
#pragma unroll
      for (int t = 0; t < 2; ++t) {
        bf16x8 k0 = *(const bf16x8*)&lKb[kbase + t * 1024 + g0];
        bf16x8 k1 = *(const bf16x8*)&lKb[kbase + t * 1024 + g1];
        s[t] = __builtin_amdgcn_mfma_f32_16x16x32_bf16(k0, qf[0], s[t], 0, 0, 0);
        s[t] = __builtin_amdgcn_mfma_f32_16x16x32_bf16(k1, qf[1], s[t], 0, 0, 0);
      }
      const int qq = qw + fr;
      const bool needmask = (kb + 31) > qw;
#pragma unroll
      for (int t = 0; t < 2; ++t) {
        bf16x4 pk;
#pragma unroll
        for (int r = 0; r < 4; ++r) {
          float v = fmaf(s[t][r], SCALE_LOG2E, -FIXED_MAX);
          if (needmask && (kb + t * 16 + fq * 4 + r > qq)) v = -1e30f;
          pk[r] = (bf16_t)__builtin_amdgcn_exp2f(v);
        }
        *(bf16x4*)&lPw[pwr + t * 16] = pk;
      }
      bf16x8 pf = *(const bf16x8*)&lPw[prd];
#pragma unroll
      for (int dt = 0; dt < 4; ++dt) {
        bf16x8 vf = *(const bf16x8*)&lVb[vbase + dt * 1024 + vg0];
        o[dt] = __builtin_amdgcn_mfma_f32_16x16x32_bf16(vf, pf, o[dt], 0, 0, 0);
      }
      liacc = __builtin_amdgcn_mfma_f32_16x16x32_bf16(ones, pf, liacc, 0, 0, 0);
    };

    int kt = 0;
#pragma unroll 1
    while (true) {
      __builtin_amdgcn_s_barrier();
      async_load16(kp, &lK[1][w * 512]);
      async_load16(vp, &lV[1][w * 512]);
      if (kt + 2 <= qt) { kp += 64 * 3072; vp += 64; }
      asm volatile("s_waitcnt vmcnt(2)" ::: "memory");
      __builtin_amdgcn_s_barrier();
      __builtin_amdgcn_sched_barrier(0);
      compute(kt, 0);
      if (++kt > qt) break;
      __builtin_amdgcn_s_barrier();
      async_load16(kp, &lK[0][w * 512]);
      async_load16(vp, &lV[0][w * 512]);
      if (kt + 2 <= qt) { kp += 64 * 3072; vp += 64; }
      asm volatile("s_waitcnt vmcnt(2)" ::: "memory");
      __builtin_amdgcn_s_barrier();
      __builtin_amdgcn_sched_barrier(0);
      compute(kt, 1);
      if (++kt > qt) break;
    }

    // key-half reduction: kh=1 writes partials, kh=0 adds + stores
    __syncthreads();   // also drains the final junk prefetch (vmcnt(0) before barrier)
    if (kh) {
#pragma unroll
      for (int dt = 0; dt < 4; ++dt)
        *(f32x4*)&lRed[qq4][fr][dt * 16 + fq * 4] = o[dt];
      if (fq == 0) lRed[qq4][fr][64] = liacc[0];
    }
    __syncthreads();
    if (!kh) {
      const float lsum = liacc[0] + lRed[qq4][fr][64];
      const float inv = 1.f / lsum;
      bf16_t* cb = ctx + (size_t)(b * 2048 + qw + fr) * 1024 + h * 64;
#pragma unroll
      for (int dt = 0; dt < 4; ++dt) {
        f32x4 v = o[dt] + *(f32x4*)&lRed[qq4][fr][dt * 16 + fq * 4];
        bf16x4 ov;
#pragma unroll
        for (int r = 0; r < 4; ++r) ov[r] = (bf16_t)(v[r] * inv);
        *(bf16x4*)(cb + dt * 16 + fq * 4) = ov;
      }
    }
  }
}

extern "C" void kernel_launch(void* const* d_in, const int* in_sizes, int n_in,
                              void* d_out, int out_size, void* d_ws, size_t ws_size,
                              hipStream_t stream) {
  const float* x  = (const float*)d_in[0];
  const float* q  = (const float*)d_in[1];
  const float* WQ = (const float*)d_in[2];
  const float* WK = (const float*)d_in[3];
  const float* WV = (const float*)d_in[4];
  const float* WO = (const float*)d_in[5];
  float* out = (float*)d_out;

  bf16_t* qb  = (bf16_t*)d_ws;
  bf16_t* xb  = qb + 4194304;
  bf16_t* wt  = xb + 4194304;
  bf16_t* qkv = wt + 4194304;
  bf16_t* vtp = qkv + (size_t)4096 * 3072;
  bf16_t* ctx = vtp + 4194304;

  prep<<<dim3(5120), 256, 0, stream>>>(x, q, WQ, WK, WV, WO, xb, qb, wt);
  gemm128<0><<<dim3(24, 32), 256, 0, stream>>>(qb, xb, wt, qkv, vtp, nullptr);
  attn8w<<<dim3(32, 16), 512, 0, stream>>>(qkv, vtp, ctx);
  gemm128<2><<<dim3(16, 32), 256, 0, stream>>>(ctx, ctx, wt + (size_t)3072 * 1024,
                                               nullptr, nullptr, out);
}